// Round 1
// baseline (222.062 us; speedup 1.0000x reference)
//
#include <hip/hip_runtime.h>

#define N_ATOMS 4096
#define CUTOFF 0.5f
#define PAIRS_PER_THREAD 4

// S(i) = number of pairs in rows < i of the strict upper triangle
__device__ __forceinline__ int row_start(int i) {
    return i * (N_ATOMS - 1) - (i * (i - 1)) / 2;
}

__global__ __launch_bounds__(256) void nbr_kernel(
    const float* __restrict__ pos,
    const float* __restrict__ box,
    float4* __restrict__ out,
    int n_pairs)
{
    // orthogonal box: diagonal of box_vectors
    const float Lx = box[0], Ly = box[4], Lz = box[8];
    const float hx = 0.5f * Lx, hy = 0.5f * Ly, hz = 0.5f * Lz;

    int p = (blockIdx.x * blockDim.x + threadIdx.x) * PAIRS_PER_THREAD;
    if (p >= n_pairs) return;

    // Analytic inversion of flat triu pair index -> (i, j).
    // i = floor(((2N-1) - sqrt((2N-1)^2 - 8p)) / 2), with integer fixup
    // because (2N-1)^2 - 8p (up to 6.7e7) is not exactly representable in f32.
    unsigned D = (2u * N_ATOMS - 1) * (2u * N_ATOMS - 1) - 8u * (unsigned)p;
    float t = sqrtf((float)D);
    int i = (int)(((float)(2 * N_ATOMS - 1) - t) * 0.5f);
    if (i < 0) i = 0;
    if (i > N_ATOMS - 2) i = N_ATOMS - 2;
    while (row_start(i + 1) <= p) ++i;   // fixup: at most a couple of steps
    while (row_start(i) > p) --i;
    int j = p - row_start(i) + i + 1;

    float xi = pos[3 * i], yi = pos[3 * i + 1], zi = pos[3 * i + 2];

    int pend = min(p + PAIRS_PER_THREAD, n_pairs);
    for (; p < pend; ++p) {
        float xj = pos[3 * j], yj = pos[3 * j + 1], zj = pos[3 * j + 2];
        float rx = xi - xj, ry = yi - yj, rz = zi - zj;

        // periodic minimum image: remainder(r + half, L) - half
        // fmodf (trunc-rem) + negative fixup == jnp.remainder semantics
        float wx = fmodf(rx + hx, Lx); if (wx < 0.0f) wx += Lx; wx -= hx;
        float wy = fmodf(ry + hy, Ly); if (wy < 0.0f) wy += Ly; wy -= hy;
        float wz = fmodf(rz + hz, Lz); if (wz < 0.0f) wz += Lz; wz -= hz;

        float d = sqrtf(wx * wx + wy * wy + wz * wz);
        float m = (d <= CUTOFF) ? 1.0f : 0.0f;

        out[p] = make_float4(wx * m, wy * m, wz * m, d * m);

        // advance to next pair in triu order
        if (++j == N_ATOMS) {
            ++i;
            j = i + 1;
            xi = pos[3 * i]; yi = pos[3 * i + 1]; zi = pos[3 * i + 2];
        }
    }
}

extern "C" void kernel_launch(void* const* d_in, const int* in_sizes, int n_in,
                              void* d_out, int out_size, void* d_ws, size_t ws_size,
                              hipStream_t stream) {
    const float* pos = (const float*)d_in[0];   // [4096, 3] f32
    const float* box = (const float*)d_in[1];   // [3, 3] f32
    // d_in[2]/d_in[3] (i_pairs/j_pairs) are intentionally unread: triu order
    // is reconstructed analytically, saving 67 MB of HBM reads.
    int n_pairs = in_sizes[2];

    float4* out = (float4*)d_out;               // [n_pairs, 4] f32

    const int threads = 256;
    const int pairs_per_block = threads * PAIRS_PER_THREAD;
    const int blocks = (n_pairs + pairs_per_block - 1) / pairs_per_block;

    nbr_kernel<<<blocks, threads, 0, stream>>>(pos, box, out, n_pairs);
}

// Round 2
// 180.375 us; speedup vs baseline: 1.2311x; 1.2311x over previous
//
#include <hip/hip_runtime.h>

#define N_ATOMS 4096
#define CUTOFF 0.5f

typedef float f32x4 __attribute__((ext_vector_type(4)));

// S(i) = number of pairs in rows < i of the strict upper triangle
__device__ __forceinline__ int row_start(int i) {
    return i * (N_ATOMS - 1) - (i * (i - 1)) / 2;
}

__global__ __launch_bounds__(256) void nbr_kernel(
    const float* __restrict__ pos,
    const float* __restrict__ box,
    f32x4* __restrict__ out,
    int n_pairs)
{
    // orthogonal box: diagonal of box_vectors
    const float Lx = box[0], Ly = box[4], Lz = box[8];
    const float hx = 0.5f * Lx, hy = 0.5f * Ly, hz = 0.5f * Lz;

    const int p = blockIdx.x * blockDim.x + threadIdx.x;
    if (p >= n_pairs) return;

    // Analytic inversion of flat triu pair index -> (i, j).
    // i = floor(((2N-1) - sqrt((2N-1)^2 - 8p)) / 2), with integer fixup
    // because (2N-1)^2 - 8p (up to 6.7e7) exceeds f32's 24-bit mantissa.
    unsigned D = (2u * N_ATOMS - 1) * (2u * N_ATOMS - 1) - 8u * (unsigned)p;
    float t = sqrtf((float)D);
    int i = (int)(((float)(2 * N_ATOMS - 1) - t) * 0.5f);
    if (i < 0) i = 0;
    if (i > N_ATOMS - 2) i = N_ATOMS - 2;
    while (row_start(i + 1) <= p) ++i;   // fixup: at most a couple steps
    while (row_start(i) > p) --i;
    const int j = p - row_start(i) + i + 1;

    const float xi = pos[3 * i], yi = pos[3 * i + 1], zi = pos[3 * i + 2];
    const float xj = pos[3 * j], yj = pos[3 * j + 1], zj = pos[3 * j + 2];

    float rx = xi - xj, ry = yi - yj, rz = zi - zj;

    // periodic minimum image: remainder(r + half, L) - half
    // fmodf (trunc-rem) + negative fixup == jnp.remainder semantics
    float wx = fmodf(rx + hx, Lx); if (wx < 0.0f) wx += Lx; wx -= hx;
    float wy = fmodf(ry + hy, Ly); if (wy < 0.0f) wy += Ly; wy -= hy;
    float wz = fmodf(rz + hz, Lz); if (wz < 0.0f) wz += Lz; wz -= hz;

    const float d = sqrtf(wx * wx + wy * wy + wz * wz);
    const float m = (d <= CUTOFF) ? 1.0f : 0.0f;

    f32x4 v;
    v.x = wx * m; v.y = wy * m; v.z = wz * m; v.w = d * m;

    // Coalesced (lane-consecutive 16B -> 1KB/wave) + nontemporal: the 134MB
    // write stream has no reuse; keep it out of L2 where positions live.
    __builtin_nontemporal_store(v, &out[p]);
}

extern "C" void kernel_launch(void* const* d_in, const int* in_sizes, int n_in,
                              void* d_out, int out_size, void* d_ws, size_t ws_size,
                              hipStream_t stream) {
    const float* pos = (const float*)d_in[0];   // [4096, 3] f32
    const float* box = (const float*)d_in[1];   // [3, 3] f32
    // d_in[2]/d_in[3] (i_pairs/j_pairs) intentionally unread: triu order is
    // reconstructed analytically, saving 67 MB of HBM reads.
    const int n_pairs = in_sizes[2];

    f32x4* out = (f32x4*)d_out;                 // [n_pairs, 4] f32

    const int threads = 256;
    const int blocks = (n_pairs + threads - 1) / threads;

    nbr_kernel<<<blocks, threads, 0, stream>>>(pos, box, out, n_pairs);
}

// Round 3
// 171.300 us; speedup vs baseline: 1.2963x; 1.0530x over previous
//
#include <hip/hip_runtime.h>

#define N_ATOMS 4096
#define CUTOFF 0.5f

typedef float f32x4 __attribute__((ext_vector_type(4)));

// S(i) = number of pairs in rows < i of the strict upper triangle
__device__ __forceinline__ int row_start(int i) {
    return i * (N_ATOMS - 1) - (i * (i - 1)) / 2;
}

__global__ __launch_bounds__(256) void nbr_kernel(
    const float* __restrict__ pos,
    const float* __restrict__ box,
    f32x4* __restrict__ out,
    int n_pairs)
{
    // orthogonal box: diagonal of box_vectors
    const float Lx = box[0], Ly = box[4], Lz = box[8];
    const float hx = 0.5f * Lx, hy = 0.5f * Ly, hz = 0.5f * Lz;

    const int p = blockIdx.x * blockDim.x + threadIdx.x;
    if (p >= n_pairs) return;

    // Analytic inversion of flat triu pair index -> (i, j).
    // i = floor(((2N-1) - sqrt((2N-1)^2 - 8p)) / 2), with integer fixup
    // because (2N-1)^2 - 8p (up to 6.7e7) exceeds f32's 24-bit mantissa.
    unsigned D = (2u * N_ATOMS - 1) * (2u * N_ATOMS - 1) - 8u * (unsigned)p;
    float t = sqrtf((float)D);
    int i = (int)(((float)(2 * N_ATOMS - 1) - t) * 0.5f);
    if (i < 0) i = 0;
    if (i > N_ATOMS - 2) i = N_ATOMS - 2;
    while (row_start(i + 1) <= p) ++i;   // fixup: at most a couple steps
    while (row_start(i) > p) --i;
    const int j = p - row_start(i) + i + 1;

    const float xi = pos[3 * i], yi = pos[3 * i + 1], zi = pos[3 * i + 2];
    const float xj = pos[3 * j], yj = pos[3 * j + 1], zj = pos[3 * j + 2];

    // Range-bounded periodic wrap, bit-identical to
    // jnp.remainder(r + half, L) - half for r in (-L, L):
    //   t = r + half in (-half, 3*half)
    //   t >= L  -> t - L   (exact: fmod's exact remainder equals this subtract)
    //   t <  0  -> t + L   (same fp add jnp.remainder's sign-fixup performs)
    // Replaces ~40-inst __ocml_fmod_f32 with 2 VALU ops per component.
    float tx = (xi - xj) + hx;
    tx = (tx >= Lx) ? tx - Lx : tx;
    tx = (tx <  0.0f) ? tx + Lx : tx;
    float wx = tx - hx;

    float ty = (yi - yj) + hy;
    ty = (ty >= Ly) ? ty - Ly : ty;
    ty = (ty <  0.0f) ? ty + Ly : ty;
    float wy = ty - hy;

    float tz = (zi - zj) + hz;
    tz = (tz >= Lz) ? tz - Lz : tz;
    tz = (tz <  0.0f) ? tz + Lz : tz;
    float wz = tz - hz;

    const float d = sqrtf(wx * wx + wy * wy + wz * wz);
    const float m = (d <= CUTOFF) ? 1.0f : 0.0f;

    f32x4 v;
    v.x = wx * m; v.y = wy * m; v.z = wz * m; v.w = d * m;

    // Coalesced (lane-consecutive 16B -> 1KB/wave) + nontemporal: the 134MB
    // write stream has no reuse; keep it out of L2 where positions live.
    __builtin_nontemporal_store(v, &out[p]);
}

extern "C" void kernel_launch(void* const* d_in, const int* in_sizes, int n_in,
                              void* d_out, int out_size, void* d_ws, size_t ws_size,
                              hipStream_t stream) {
    const float* pos = (const float*)d_in[0];   // [4096, 3] f32
    const float* box = (const float*)d_in[1];   // [3, 3] f32
    // d_in[2]/d_in[3] (i_pairs/j_pairs) intentionally unread: triu order is
    // reconstructed analytically, saving 67 MB of HBM reads.
    const int n_pairs = in_sizes[2];

    f32x4* out = (f32x4*)d_out;                 // [n_pairs, 4] f32

    const int threads = 256;
    const int blocks = (n_pairs + threads - 1) / threads;

    nbr_kernel<<<blocks, threads, 0, stream>>>(pos, box, out, n_pairs);
}